// Round 4
// baseline (424.346 us; speedup 1.0000x reference)
//
#include <hip/hip_runtime.h>
#include <hip/hip_bf16.h>
#include <stdint.h>

// ---------------------------------------------------------------------------
// CapsuleLayerSemantic: LN -> per-adapter (W1,relu,W2) -> capsule squash over A
// B=16 S=2048 NX=1024 A=20 H=50 O=3.  M = 32768 tokens.
// R4: LN fused into GEMM (stats kernel + in-GEMM normalize/cvt); packed
//     N=1024 (n=a*50+h, no pad) with atomic partial-adapter epilogue;
//     ws 70MB -> 2.3MB.  4 kernels: stats, prep_w, gemm, squash.
// ---------------------------------------------------------------------------

typedef _Float16 h8 __attribute__((ext_vector_type(8)));
typedef float f4 __attribute__((ext_vector_type(4)));
typedef __attribute__((address_space(1))) void gvoid;
typedef __attribute__((address_space(3))) void lvoid;

__device__ __forceinline__ void cp16(const void* g, void* l) {
  __builtin_amdgcn_global_load_lds((gvoid*)g, (lvoid*)l, 16, 0, 0);
}

// ---------------- kernel 1: LN stats (inv, -mu*inv) per token ---------------
__global__ __launch_bounds__(256) void stats_kernel(const float* __restrict__ x,
                                                    float2* __restrict__ st) {
  const int t = threadIdx.x, w = t >> 6, l = t & 63;
  const int tok = blockIdx.x * 4 + w;
  const float4* xr = (const float4*)(x + (size_t)tok * 1024);
  float s1 = 0.f, s2 = 0.f;
#pragma unroll
  for (int i = 0; i < 4; ++i) {
    float4 v = xr[l + i * 64];
    s1 += v.x + v.y + v.z + v.w;
    s2 += v.x * v.x + v.y * v.y + v.z * v.z + v.w * v.w;
  }
#pragma unroll
  for (int m = 32; m > 0; m >>= 1) {
    s1 += __shfl_xor(s1, m);
    s2 += __shfl_xor(s2, m);
  }
  if (l == 0) {
    const float mu = s1 * 0.0009765625f;
    const float var = s2 * 0.0009765625f - mu * mu;
    const float inv = rsqrtf(var + 1e-5f);
    st[tok] = make_float2(inv, -mu * inv);
  }
}

// ---------------- kernel 2: prep — packed wB[a*50+h][k] fp16, off partials --
// grid (20,16): a, k-chunk of 64. Coalesced W1 tile -> LDS; each thread
// covers k = q*16..q*16+15 via two 16B stores. Rows 1000..1023 zeroed by a==0.
__global__ __launch_bounds__(256) void prep_w(const float* __restrict__ ln_g,
                                              const float* __restrict__ ln_b,
                                              const float* __restrict__ W1,
                                              _Float16* __restrict__ wB,
                                              float* __restrict__ offacc) {
  const int a = blockIdx.x, k0 = blockIdx.y * 64, t = threadIdx.x;
  __shared__ float tw[3200];  // W1[a][k0..k0+64][0..50]
  __shared__ float gg[64], bb[64];
  const float* src = W1 + (size_t)(a * 1024 + k0) * 50;
  for (int i = t; i < 3200; i += 256) tw[i] = src[i];
  if (t < 64) gg[t] = ln_g[a * 1024 + k0 + t];
  else if (t < 128) bb[t - 64] = ln_b[a * 1024 + k0 + (t - 64)];
  __syncthreads();
  const int h = t & 63, q = t >> 6;
  if (h < 50) {
    float po = 0.f;
#pragma unroll
    for (int half = 0; half < 2; ++half) {
      union { _Float16 hh[8]; uint4 u; } pk;
#pragma unroll
      for (int j = 0; j < 8; ++j) {
        const int k = q * 16 + half * 8 + j;
        const float wv = tw[k * 50 + h];
        pk.hh[j] = (_Float16)(gg[k] * wv);
        po += bb[k] * wv;
      }
      *(uint4*)(wB + (size_t)(a * 50 + h) * 1024 + k0 + q * 16 + half * 8) =
          pk.u;
    }
    if (po != 0.f) atomicAdd(&offacc[a * 50 + h], po);
  }
  if (a == 0 && t < 192) {  // zero pad rows 1000..1023 for this k-chunk
    const uint4 z = {0, 0, 0, 0};
    *(uint4*)(wB + (size_t)(1000 + (t >> 3)) * 1024 + k0 + (t & 7) * 8) = z;
  }
}

// ---------------- kernel 3: GEMM (LN fused on A) + partial epilogue ---------
// grid (8, 256): nb = 128 packed columns, mb = 128 tokens. BK=64,
// mfma_f32_16x16x32_f16, 4 waves 2x2. A staged fp32->normalize->fp16 via
// ds_write_b128 into the XOR-swizzled layout; B via global_load_lds.
// Epilogue: h=relu(acc+off) -> LDS (2 passes of 64 rows), per-(token,adapter-
// segment) W2 dot, atomicAdd into zero-initialized out (b2 added in squash).
__global__ __launch_bounds__(256, 4) void gemm_kernel(
    const float* __restrict__ x, const float2* __restrict__ st,
    const _Float16* __restrict__ wB, const float* __restrict__ offacc,
    const float* __restrict__ b1, const float* __restrict__ W2,
    float* __restrict__ out) {
  __shared__ __align__(16) char smem[36448];
  // [0,16384) sA | [16384,32768) sB | reuse: hm=float[64][133]=34048
  // [34048,36448) w2s: 600 f32 (W2 for adapters a0..a0+3)
  const int nb = blockIdx.x, mb = blockIdx.y;
  const int t = threadIdx.x, w = t >> 6, l = t & 63;

  const int a0 = (nb * 128) / 50;
  float* w2s = (float*)(smem + 34048);
  for (int i = t; i < 600; i += 256) {
    const int j = i / 150, a = a0 + j;
    w2s[i] = (a < 20) ? W2[a * 150 + (i - j * 150)] : 0.f;
  }

  // A staging: thread -> (row, k-half); 32 fp32 -> 4x ds_write_b128
  const int arow = t >> 1, ahf = t & 1;
  const float2 sb = st[mb * 128 + arow];
  const float* gx = x + (size_t)(mb * 128 + arow) * 1024 + ahf * 32;
  char* swA = smem + arow * 128;
  const int rx = arow & 7;

  // B staging via global_load_lds: chunk=8 rows, phys slot l&7 holds logical
  // slot (l&7)^(l>>3)
  const int lr = l >> 3;
  const int ksl = (l & 7) ^ lr;
  const _Float16* gB = wB + (size_t)(nb * 128 + lr) * 1024 + ksl * 8;

  const int rowA = ((w >> 1) * 64) + (l & 15);
  const int rowB = ((w & 1) * 64) + (l & 15);
  const int kq = l >> 4;
  const int xa = rowA & 7, xb = rowB & 7;
  const char* pA = smem + rowA * 128;
  const char* pB = smem + 16384 + rowB * 128;

  f4 acc[4][4];
  {
    f4 z = {0.f, 0.f, 0.f, 0.f};
#pragma unroll
    for (int mt = 0; mt < 4; ++mt)
#pragma unroll
      for (int nt = 0; nt < 4; ++nt) acc[mt][nt] = z;
  }

  for (int kt = 0; kt < 16; ++kt) {
#pragma unroll
    for (int i = 0; i < 4; ++i)
      cp16(gB + (size_t)(w * 4 + i) * 8192 + kt * 64,
           smem + 16384 + (w * 4 + i) * 1024);
    const float4* px = (const float4*)(gx + kt * 64);
#pragma unroll
    for (int i = 0; i < 4; ++i) {
      const float4 u0 = px[2 * i], u1 = px[2 * i + 1];
      union { _Float16 hh[8]; uint4 u; } pk;
      pk.hh[0] = (_Float16)fmaf(u0.x, sb.x, sb.y);
      pk.hh[1] = (_Float16)fmaf(u0.y, sb.x, sb.y);
      pk.hh[2] = (_Float16)fmaf(u0.z, sb.x, sb.y);
      pk.hh[3] = (_Float16)fmaf(u0.w, sb.x, sb.y);
      pk.hh[4] = (_Float16)fmaf(u1.x, sb.x, sb.y);
      pk.hh[5] = (_Float16)fmaf(u1.y, sb.x, sb.y);
      pk.hh[6] = (_Float16)fmaf(u1.z, sb.x, sb.y);
      pk.hh[7] = (_Float16)fmaf(u1.w, sb.x, sb.y);
      const int sl = ahf * 4 + i;
      *(uint4*)(swA + ((sl ^ rx) << 4)) = pk.u;
    }
    __syncthreads();
#pragma unroll
    for (int ks = 0; ks < 2; ++ks) {
      h8 af[4], bf[4];
      const int sl = ks * 4 + kq;
#pragma unroll
      for (int mt = 0; mt < 4; ++mt)
        af[mt] = *(const h8*)(pA + mt * 2048 + ((sl ^ xa) << 4));
#pragma unroll
      for (int nt = 0; nt < 4; ++nt)
        bf[nt] = *(const h8*)(pB + nt * 2048 + ((sl ^ xb) << 4));
#pragma unroll
      for (int mt = 0; mt < 4; ++mt)
#pragma unroll
        for (int nt = 0; nt < 4; ++nt)
          acc[mt][nt] = __builtin_amdgcn_mfma_f32_16x16x32_f16(
              af[mt], bf[nt], acc[mt][nt], 0, 0, 0);
    }
    __syncthreads();
  }

  // off_total: packed n = a*50+h -> b1[n] directly
  float offt[4];
#pragma unroll
  for (int nt = 0; nt < 4; ++nt) {
    const int n = nb * 128 + rowB + nt * 16;
    offt[nt] = offacc[n] + ((n < 1000) ? b1[n] : 0.f);
  }

  // per-thread dot assignment: 64 tokens x 4 adapter slots
  const int ml = t >> 2, j = t & 3;
  const int a = a0 + j;
  const int c0 = nb * 128;
  int cs = a * 50, ce = cs + 50;
  if (cs < c0) cs = c0;
  if (ce > c0 + 128) ce = c0 + 128;
  const bool act = (a < 20) && (cs < ce);
  const int lo = cs - c0;
  const int len = act ? (ce - cs) : 0;
  const int h0 = cs - a * 50;
  const float* wrow = w2s + j * 150 + h0 * 3;

  float* hm = (float*)smem;  // [64][133]
  const int mrl = (l >> 4) * 4;
  const int ncol = (w & 1) * 64 + (l & 15);
#pragma unroll
  for (int p = 0; p < 2; ++p) {
    if (p) __syncthreads();
    if ((w >> 1) == p) {
#pragma unroll
      for (int mt = 0; mt < 4; ++mt)
#pragma unroll
        for (int nt = 0; nt < 4; ++nt)
#pragma unroll
          for (int r = 0; r < 4; ++r)
            hm[(mrl + mt * 16 + r) * 133 + (ncol + nt * 16)] =
                fmaxf(acc[mt][nt][r] + offt[nt], 0.f);
    }
    __syncthreads();
    if (act) {
      const float* hr = hm + ml * 133 + lo;
      float o0 = 0.f, o1 = 0.f, o2 = 0.f;
      for (int i = 0; i < len; ++i) {
        const float hv = hr[i];
        o0 += hv * wrow[i * 3 + 0];
        o1 += hv * wrow[i * 3 + 1];
        o2 += hv * wrow[i * 3 + 2];
      }
      const int tok = mb * 128 + p * 64 + ml;
      const int b = tok >> 11, s = tok & 2047;
      float* op = out + ((size_t)(b * 20 + a) * 2048 + (size_t)s) * 3;
      atomicAdd(op + 0, o0);
      atomicAdd(op + 1, o1);
      atomicAdd(op + 2, o2);
    }
  }
}

// ---------------- kernel 4: +b2, capsule squash over A, in place ------------
__global__ __launch_bounds__(256) void squash_kernel(float* __restrict__ out,
                                                     const float* __restrict__ b2) {
  const int idx = blockIdx.x * 256 + threadIdx.x;  // 0 .. 16*6144-1
  const int b = idx / 6144;
  const int rem = idx - b * 6144;
  const int oi = rem % 3;
  float v[20];
  float sq = 0.f;
#pragma unroll
  for (int a = 0; a < 20; ++a) {
    v[a] = out[((size_t)(b * 20 + a)) * 6144 + rem] + b2[a * 3 + oi];
    sq += v[a] * v[a];
  }
  const float f = sqrtf(sq) / (1.f + sq);  // (sq/(1+sq))*rsqrt(sq), safe at 0
#pragma unroll
  for (int a = 0; a < 20; ++a)
    out[((size_t)(b * 20 + a)) * 6144 + rem] = v[a] * f;
}

// ---------------------------------------------------------------------------
extern "C" void kernel_launch(void* const* d_in, const int* in_sizes, int n_in,
                              void* d_out, int out_size, void* d_ws,
                              size_t ws_size, hipStream_t stream) {
  const float* x    = (const float*)d_in[0];  // [16,2048,1024]
  const float* ln_g = (const float*)d_in[1];  // [20,1024]
  const float* ln_b = (const float*)d_in[2];  // [20,1024]
  const float* W1   = (const float*)d_in[3];  // [20,1024,50]
  const float* b1   = (const float*)d_in[4];  // [20,50]
  const float* W2   = (const float*)d_in[5];  // [20,50,3]
  const float* b2   = (const float*)d_in[6];  // [20,3]
  float* out = (float*)d_out;                 // [16,20,6144]

  char* ws = (char*)d_ws;
  float* offacc = (float*)ws;                       // 1024 f32 @ 0
  float2* stw   = (float2*)(ws + 4096);             // 32768 float2 (256 KB)
  _Float16* wBw = (_Float16*)(ws + 4096 + 262144);  // 1024*1024 fp16 (2 MB)

  hipMemsetAsync(offacc, 0, 1024 * sizeof(float), stream);
  hipMemsetAsync(out, 0, (size_t)out_size * sizeof(float), stream);
  stats_kernel<<<8192, 256, 0, stream>>>(x, stw);
  prep_w<<<dim3(20, 16), 256, 0, stream>>>(ln_g, ln_b, W1, wBw, offacc);
  gemm_kernel<<<dim3(8, 256), 256, 0, stream>>>(x, stw, wBw, offacc, b1, W2,
                                                out);
  squash_kernel<<<384, 256, 0, stream>>>(out, b2);
}

// Round 5
// 391.591 us; speedup vs baseline: 1.0836x; 1.0836x over previous
//
#include <hip/hip_runtime.h>
#include <hip/hip_bf16.h>
#include <stdint.h>

// ---------------------------------------------------------------------------
// CapsuleLayerSemantic: LN -> per-adapter (W1,relu,W2) -> capsule squash over A
// B=16 S=2048 NX=1024 A=20 H=50 O=3.  M = 32768 tokens.
// R5: revert LN-in-GEMM (R4's fp32 re-read doubled FETCH). xn fp16 workspace
//     again; packed N=1024 GEMM (8 nb) + atomic epilogue; XCD-aware swizzle
//     (each XCD walks all nb for one mb -> A-tile L2 reuse); helpers merged
//     into one pre-kernel (LN blocks + 20 prep blocks, exact offacc).
// ---------------------------------------------------------------------------

typedef _Float16 h8 __attribute__((ext_vector_type(8)));
typedef float f4 __attribute__((ext_vector_type(4)));
typedef __attribute__((address_space(1))) void gvoid;
typedef __attribute__((address_space(3))) void lvoid;

__device__ __forceinline__ void cp16(const void* g, void* l) {
  __builtin_amdgcn_global_load_lds((gvoid*)g, (lvoid*)l, 16, 0, 0);
}

// ---------------- kernel 1: fused pre — LN->fp16 xn  +  W1 prep -------------
// blocks [0,8192): wave-per-token LN (no LDS, no barriers).
// blocks [8192,8212): per-adapter W1*ln_g transpose -> wB fp16 packed rows,
//   off[a*50+h] = sum_k ln_b[a][k]*W1[a][k][h] computed exactly (no atomics).
__global__ __launch_bounds__(256) void pre_kernel(
    const float* __restrict__ x, _Float16* __restrict__ xn,
    const float* __restrict__ ln_g, const float* __restrict__ ln_b,
    const float* __restrict__ W1, _Float16* __restrict__ wB,
    float* __restrict__ offacc) {
  const int t = threadIdx.x;
  if (blockIdx.x < 8192) {
    const int w = t >> 6, l = t & 63;
    const int tok = blockIdx.x * 4 + w;
    const float4* xr = (const float4*)(x + (size_t)tok * 1024);
    float4 v0 = xr[l * 2], v1 = xr[l * 2 + 1];
    float4 v2 = xr[128 + l * 2], v3 = xr[128 + l * 2 + 1];
    float s1 = (v0.x + v0.y + v0.z + v0.w) + (v1.x + v1.y + v1.z + v1.w) +
               (v2.x + v2.y + v2.z + v2.w) + (v3.x + v3.y + v3.z + v3.w);
    float s2 = v0.x * v0.x + v0.y * v0.y + v0.z * v0.z + v0.w * v0.w;
    s2 += v1.x * v1.x + v1.y * v1.y + v1.z * v1.z + v1.w * v1.w;
    s2 += v2.x * v2.x + v2.y * v2.y + v2.z * v2.z + v2.w * v2.w;
    s2 += v3.x * v3.x + v3.y * v3.y + v3.z * v3.z + v3.w * v3.w;
#pragma unroll
    for (int m = 32; m > 0; m >>= 1) {
      s1 += __shfl_xor(s1, m);
      s2 += __shfl_xor(s2, m);
    }
    const float mu = s1 * 0.0009765625f;
    const float var = s2 * 0.0009765625f - mu * mu;
    const float inv = rsqrtf(var + 1e-5f);
    union { _Float16 h[8]; uint4 u; } p;
    _Float16* xw = xn + (size_t)tok * 1024 + l * 8;
    p.h[0] = (_Float16)((v0.x - mu) * inv); p.h[1] = (_Float16)((v0.y - mu) * inv);
    p.h[2] = (_Float16)((v0.z - mu) * inv); p.h[3] = (_Float16)((v0.w - mu) * inv);
    p.h[4] = (_Float16)((v1.x - mu) * inv); p.h[5] = (_Float16)((v1.y - mu) * inv);
    p.h[6] = (_Float16)((v1.z - mu) * inv); p.h[7] = (_Float16)((v1.w - mu) * inv);
    *(uint4*)xw = p.u;
    p.h[0] = (_Float16)((v2.x - mu) * inv); p.h[1] = (_Float16)((v2.y - mu) * inv);
    p.h[2] = (_Float16)((v2.z - mu) * inv); p.h[3] = (_Float16)((v2.w - mu) * inv);
    p.h[4] = (_Float16)((v3.x - mu) * inv); p.h[5] = (_Float16)((v3.y - mu) * inv);
    p.h[6] = (_Float16)((v3.z - mu) * inv); p.h[7] = (_Float16)((v3.w - mu) * inv);
    *(uint4*)(xw + 512) = p.u;
    return;
  }
  // ---- prep branch: one block per adapter ----
  const int a = blockIdx.x - 8192;
  __shared__ float tw[3200], gg[64], bb[64], red[256];
  const int h = t & 63, q = t >> 6;
  float po = 0.f;
  for (int c = 0; c < 16; ++c) {
    const int k0 = c * 64;
    __syncthreads();  // protect tw/gg/bb from previous iteration's readers
    const float* src = W1 + (size_t)(a * 1024 + k0) * 50;
    for (int i = t; i < 3200; i += 256) tw[i] = src[i];
    if (t < 64) gg[t] = ln_g[a * 1024 + k0 + t];
    else if (t < 128) bb[t - 64] = ln_b[a * 1024 + k0 + (t - 64)];
    __syncthreads();
    if (h < 50) {
#pragma unroll
      for (int half = 0; half < 2; ++half) {
        union { _Float16 hh[8]; uint4 u; } pk;
#pragma unroll
        for (int j = 0; j < 8; ++j) {
          const int k = q * 16 + half * 8 + j;
          const float wv = tw[k * 50 + h];
          pk.hh[j] = (_Float16)(gg[k] * wv);
          po += bb[k] * wv;
        }
        *(uint4*)(wB + (size_t)(a * 50 + h) * 1024 + k0 + q * 16 + half * 8) =
            pk.u;
      }
    }
  }
  red[t] = po;
  __syncthreads();
  if (t < 50)
    offacc[a * 50 + t] = red[t] + red[64 + t] + red[128 + t] + red[192 + t];
  if (a == 0) {
    const uint4 z = {0, 0, 0, 0};
    for (int i = t; i < 3072; i += 256)  // zero pad rows 1000..1023
      *(uint4*)(wB + (size_t)1000 * 1024 + i * 8) = z;
    if (t < 24) offacc[1000 + t] = 0.f;
  }
}

// ---------------- kernel 2: GEMM + partial-adapter epilogue -----------------
// 1D grid 2048, swizzled: xcd=g&7, i=g>>3, nb=i&7, mb=xcd*32+(i>>3) — under
// round-robin block->XCD dispatch each XCD walks all 8 nb for one mb, so the
// 256KB A-tile is L2-resident for its 8 uses and wB (2MB) stays L2-resident.
// 128x128 tile, BK=64, mfma_f32_16x16x32_f16, 4 waves 2x2, XOR-swizzled LDS,
// both A and B staged via global_load_lds width-16.
__global__ __launch_bounds__(256, 4) void gemm_kernel(
    const _Float16* __restrict__ xn, const _Float16* __restrict__ wB,
    const float* __restrict__ offacc, const float* __restrict__ b1,
    const float* __restrict__ W2, float* __restrict__ out) {
  __shared__ __align__(16) char smem[36448];
  // [0,16384) sA | [16384,32768) sB | reuse: hm=float[64][133]=34048
  // [34048,36448) w2s: 600 f32 (W2 for adapters a0..a0+3)
  const int g = blockIdx.x;
  const int xcd = g & 7, i0 = g >> 3;
  const int nb = i0 & 7;
  const int mb = xcd * 32 + (i0 >> 3);
  const int t = threadIdx.x, w = t >> 6, l = t & 63;

  const int a0 = (nb * 128) / 50;
  float* w2s = (float*)(smem + 34048);
  for (int i = t; i < 600; i += 256) {
    const int j = i / 150, a = a0 + j;
    w2s[i] = (a < 20) ? W2[a * 150 + (i - j * 150)] : 0.f;
  }

  // staging: chunk = 8 rows (1KB); lane -> row chunk*8+(l>>3), phys slot l&7
  // holding logical k-slot (l&7)^(l>>3).
  const int lr = l >> 3;
  const int ksl = (l & 7) ^ lr;
  const _Float16* gA = xn + (size_t)(mb * 128 + lr) * 1024 + ksl * 8;
  const _Float16* gB = wB + (size_t)(nb * 128 + lr) * 1024 + ksl * 8;

  const int rowA = ((w >> 1) * 64) + (l & 15);
  const int rowB = ((w & 1) * 64) + (l & 15);
  const int kq = l >> 4;
  const int xa = rowA & 7, xb = rowB & 7;
  const char* pA = smem + rowA * 128;
  const char* pB = smem + 16384 + rowB * 128;

  f4 acc[4][4];
  {
    f4 z = {0.f, 0.f, 0.f, 0.f};
#pragma unroll
    for (int mt = 0; mt < 4; ++mt)
#pragma unroll
      for (int nt = 0; nt < 4; ++nt) acc[mt][nt] = z;
  }

  for (int kt = 0; kt < 16; ++kt) {
#pragma unroll
    for (int i = 0; i < 4; ++i) {
      const int chunk = w * 4 + i;
      cp16(gA + (size_t)chunk * 8192 + kt * 64, smem + chunk * 1024);
      cp16(gB + (size_t)chunk * 8192 + kt * 64, smem + 16384 + chunk * 1024);
    }
    __syncthreads();
#pragma unroll
    for (int ks = 0; ks < 2; ++ks) {
      h8 af[4], bf[4];
      const int sl = ks * 4 + kq;
#pragma unroll
      for (int mt = 0; mt < 4; ++mt)
        af[mt] = *(const h8*)(pA + mt * 2048 + ((sl ^ xa) << 4));
#pragma unroll
      for (int nt = 0; nt < 4; ++nt)
        bf[nt] = *(const h8*)(pB + nt * 2048 + ((sl ^ xb) << 4));
#pragma unroll
      for (int mt = 0; mt < 4; ++mt)
#pragma unroll
        for (int nt = 0; nt < 4; ++nt)
          acc[mt][nt] = __builtin_amdgcn_mfma_f32_16x16x32_f16(
              af[mt], bf[nt], acc[mt][nt], 0, 0, 0);
    }
    __syncthreads();
  }

  // off_total: packed n = a*50+h -> b1[n] directly; pad rows are zero.
  float offt[4];
#pragma unroll
  for (int nt = 0; nt < 4; ++nt) {
    const int n = nb * 128 + rowB + nt * 16;
    offt[nt] = offacc[n] + ((n < 1000) ? b1[n] : 0.f);
  }

  // per-thread dot assignment: 64 tokens x 4 adapter slots
  const int ml = t >> 2, j = t & 3;
  const int a = a0 + j;
  const int c0 = nb * 128;
  int cs = a * 50, ce = cs + 50;
  if (cs < c0) cs = c0;
  if (ce > c0 + 128) ce = c0 + 128;
  const bool act = (a < 20) && (cs < ce);
  const int lo = cs - c0;
  const int len = act ? (ce - cs) : 0;
  const int h0 = cs - a * 50;
  const float* wrow = w2s + j * 150 + h0 * 3;

  float* hm = (float*)smem;  // [64][133]
  const int mrl = (l >> 4) * 4;
  const int ncol = (w & 1) * 64 + (l & 15);
#pragma unroll
  for (int p = 0; p < 2; ++p) {
    if (p) __syncthreads();
    if ((w >> 1) == p) {
#pragma unroll
      for (int mt = 0; mt < 4; ++mt)
#pragma unroll
        for (int nt = 0; nt < 4; ++nt)
#pragma unroll
          for (int r = 0; r < 4; ++r)
            hm[(mrl + mt * 16 + r) * 133 + (ncol + nt * 16)] =
                fmaxf(acc[mt][nt][r] + offt[nt], 0.f);
    }
    __syncthreads();
    if (act) {
      const float* hr = hm + ml * 133 + lo;
      float o0 = 0.f, o1 = 0.f, o2 = 0.f;
      for (int i = 0; i < len; ++i) {
        const float hv = hr[i];
        o0 += hv * wrow[i * 3 + 0];
        o1 += hv * wrow[i * 3 + 1];
        o2 += hv * wrow[i * 3 + 2];
      }
      const int tok = mb * 128 + p * 64 + ml;
      const int b = tok >> 11, s = tok & 2047;
      float* op = out + ((size_t)(b * 20 + a) * 2048 + (size_t)s) * 3;
      atomicAdd(op + 0, o0);
      atomicAdd(op + 1, o1);
      atomicAdd(op + 2, o2);
    }
  }
}

// ---------------- kernel 3: +b2, capsule squash over A, in place ------------
__global__ __launch_bounds__(256) void squash_kernel(
    float* __restrict__ out, const float* __restrict__ b2) {
  const int idx = blockIdx.x * 256 + threadIdx.x;  // 0 .. 16*6144-1
  const int b = idx / 6144;
  const int rem = idx - b * 6144;
  const int oi = rem % 3;
  float v[20];
  float sq = 0.f;
#pragma unroll
  for (int a = 0; a < 20; ++a) {
    v[a] = out[((size_t)(b * 20 + a)) * 6144 + rem] + b2[a * 3 + oi];
    sq += v[a] * v[a];
  }
  const float f = sqrtf(sq) / (1.f + sq);  // (sq/(1+sq))*rsqrt(sq), safe at 0
#pragma unroll
  for (int a = 0; a < 20; ++a)
    out[((size_t)(b * 20 + a)) * 6144 + rem] = v[a] * f;
}

// ---------------------------------------------------------------------------
extern "C" void kernel_launch(void* const* d_in, const int* in_sizes, int n_in,
                              void* d_out, int out_size, void* d_ws,
                              size_t ws_size, hipStream_t stream) {
  const float* x    = (const float*)d_in[0];  // [16,2048,1024]
  const float* ln_g = (const float*)d_in[1];  // [20,1024]
  const float* ln_b = (const float*)d_in[2];  // [20,1024]
  const float* W1   = (const float*)d_in[3];  // [20,1024,50]
  const float* b1   = (const float*)d_in[4];  // [20,50]
  const float* W2   = (const float*)d_in[5];  // [20,50,3]
  const float* b2   = (const float*)d_in[6];  // [20,3]
  float* out = (float*)d_out;                 // [16,20,6144]

  char* ws = (char*)d_ws;
  float* offacc = (float*)ws;                       // 1024 f32 @ 0
  _Float16* wBw = (_Float16*)(ws + 4096);           // 1024*1024 fp16 (2 MB)
  _Float16* xnw = (_Float16*)(ws + 4096 + 2097152); // 32768*1024 fp16 (67 MB)

  hipMemsetAsync(out, 0, (size_t)out_size * sizeof(float), stream);
  pre_kernel<<<8212, 256, 0, stream>>>(x, xnw, ln_g, ln_b, W1, wBw, offacc);
  gemm_kernel<<<2048, 256, 0, stream>>>(xnw, wBw, offacc, b1, W2, out);
  squash_kernel<<<384, 256, 0, stream>>>(out, b2);
}

// Round 6
// 311.059 us; speedup vs baseline: 1.3642x; 1.2589x over previous
//
#include <hip/hip_runtime.h>
#include <hip/hip_bf16.h>
#include <stdint.h>

// ---------------------------------------------------------------------------
// CapsuleLayerSemantic: LN -> per-adapter (W1,relu,W2) -> capsule squash over A
// B=16 S=2048 NX=1024 A=20 H=50 O=3.  M = 32768 tokens.
// R6: un-merge R5's pre_kernel (20-block prep tail ran ~120us nearly alone).
//     ln_kernel (8192 blocks) + prep_w (320 blocks, packed+atomics) again;
//     keep R5's XCD-swizzled packed-N GEMM + atomic epilogue + squash.
// ---------------------------------------------------------------------------

typedef _Float16 h8 __attribute__((ext_vector_type(8)));
typedef float f4 __attribute__((ext_vector_type(4)));
typedef __attribute__((address_space(1))) void gvoid;
typedef __attribute__((address_space(3))) void lvoid;

__device__ __forceinline__ void cp16(const void* g, void* l) {
  __builtin_amdgcn_global_load_lds((gvoid*)g, (lvoid*)l, 16, 0, 0);
}

// ---------------- kernel 1: layernorm + fp16 cast (one wave per token) ------
__global__ __launch_bounds__(256) void ln_kernel(const float* __restrict__ x,
                                                 _Float16* __restrict__ xn) {
  const int t = threadIdx.x, w = t >> 6, l = t & 63;
  const int tok = blockIdx.x * 4 + w;
  const float4* xr = (const float4*)(x + (size_t)tok * 1024);
  float4 v0 = xr[l * 2], v1 = xr[l * 2 + 1];
  float4 v2 = xr[128 + l * 2], v3 = xr[128 + l * 2 + 1];
  float s1 = (v0.x + v0.y + v0.z + v0.w) + (v1.x + v1.y + v1.z + v1.w) +
             (v2.x + v2.y + v2.z + v2.w) + (v3.x + v3.y + v3.z + v3.w);
  float s2 = v0.x * v0.x + v0.y * v0.y + v0.z * v0.z + v0.w * v0.w;
  s2 += v1.x * v1.x + v1.y * v1.y + v1.z * v1.z + v1.w * v1.w;
  s2 += v2.x * v2.x + v2.y * v2.y + v2.z * v2.z + v2.w * v2.w;
  s2 += v3.x * v3.x + v3.y * v3.y + v3.z * v3.z + v3.w * v3.w;
#pragma unroll
  for (int m = 32; m > 0; m >>= 1) {
    s1 += __shfl_xor(s1, m);
    s2 += __shfl_xor(s2, m);
  }
  const float mu = s1 * 0.0009765625f;
  const float var = s2 * 0.0009765625f - mu * mu;
  const float inv = rsqrtf(var + 1e-5f);
  union { _Float16 h[8]; uint4 u; } p;
  _Float16* xw = xn + (size_t)tok * 1024 + l * 8;
  p.h[0] = (_Float16)((v0.x - mu) * inv); p.h[1] = (_Float16)((v0.y - mu) * inv);
  p.h[2] = (_Float16)((v0.z - mu) * inv); p.h[3] = (_Float16)((v0.w - mu) * inv);
  p.h[4] = (_Float16)((v1.x - mu) * inv); p.h[5] = (_Float16)((v1.y - mu) * inv);
  p.h[6] = (_Float16)((v1.z - mu) * inv); p.h[7] = (_Float16)((v1.w - mu) * inv);
  *(uint4*)xw = p.u;
  p.h[0] = (_Float16)((v2.x - mu) * inv); p.h[1] = (_Float16)((v2.y - mu) * inv);
  p.h[2] = (_Float16)((v2.z - mu) * inv); p.h[3] = (_Float16)((v2.w - mu) * inv);
  p.h[4] = (_Float16)((v3.x - mu) * inv); p.h[5] = (_Float16)((v3.y - mu) * inv);
  p.h[6] = (_Float16)((v3.z - mu) * inv); p.h[7] = (_Float16)((v3.w - mu) * inv);
  *(uint4*)(xw + 512) = p.u;
}

// ---------------- kernel 2: prep — packed wB[a*50+h][k] fp16, off partials --
// grid (20,16): a, k-chunk of 64. 320 blocks -> real TLP (R5's 20-block merge
// ran ~120us nearly alone). Coalesced W1 tile -> LDS; each thread covers
// k = q*16..q*16+15 via two 16B stores. Pad rows 1000..1023 zeroed by a==0.
__global__ __launch_bounds__(256) void prep_w(const float* __restrict__ ln_g,
                                              const float* __restrict__ ln_b,
                                              const float* __restrict__ W1,
                                              _Float16* __restrict__ wB,
                                              float* __restrict__ offacc) {
  const int a = blockIdx.x, k0 = blockIdx.y * 64, t = threadIdx.x;
  __shared__ float tw[3200];  // W1[a][k0..k0+64][0..50]
  __shared__ float gg[64], bb[64];
  const float* src = W1 + (size_t)(a * 1024 + k0) * 50;
  for (int i = t; i < 3200; i += 256) tw[i] = src[i];
  if (t < 64) gg[t] = ln_g[a * 1024 + k0 + t];
  else if (t < 128) bb[t - 64] = ln_b[a * 1024 + k0 + (t - 64)];
  __syncthreads();
  const int h = t & 63, q = t >> 6;
  if (h < 50) {
    float po = 0.f;
#pragma unroll
    for (int half = 0; half < 2; ++half) {
      union { _Float16 hh[8]; uint4 u; } pk;
#pragma unroll
      for (int j = 0; j < 8; ++j) {
        const int k = q * 16 + half * 8 + j;
        const float wv = tw[k * 50 + h];
        pk.hh[j] = (_Float16)(gg[k] * wv);
        po += bb[k] * wv;
      }
      *(uint4*)(wB + (size_t)(a * 50 + h) * 1024 + k0 + q * 16 + half * 8) =
          pk.u;
    }
    if (po != 0.f) atomicAdd(&offacc[a * 50 + h], po);
  }
  if (a == 0 && t < 192) {  // zero pad rows 1000..1023 for this k-chunk
    const uint4 z = {0, 0, 0, 0};
    *(uint4*)(wB + (size_t)(1000 + (t >> 3)) * 1024 + k0 + (t & 7) * 8) = z;
  }
}

// ---------------- kernel 3: GEMM + partial-adapter epilogue -----------------
// 1D grid 2048, swizzled: xcd=g&7, i=g>>3, nb=i&7, mb=xcd*32+(i>>3) — under
// round-robin block->XCD dispatch each XCD walks all 8 nb for one mb, so the
// 256KB A-tile is fetched into L2 once per mb globally and wB (2MB) stays
// L2-resident. 128x128 tile, BK=64, mfma_f32_16x16x32_f16, 4 waves 2x2,
// XOR-swizzled LDS, A and B staged via global_load_lds width-16.
__global__ __launch_bounds__(256, 4) void gemm_kernel(
    const _Float16* __restrict__ xn, const _Float16* __restrict__ wB,
    const float* __restrict__ offacc, const float* __restrict__ b1,
    const float* __restrict__ W2, float* __restrict__ out) {
  __shared__ __align__(16) char smem[36448];
  // [0,16384) sA | [16384,32768) sB | reuse: hm=float[64][133]=34048
  // [34048,36448) w2s: 600 f32 (W2 for adapters a0..a0+3)
  const int g = blockIdx.x;
  const int xcd = g & 7, i0 = g >> 3;
  const int nb = i0 & 7;
  const int mb = xcd * 32 + (i0 >> 3);
  const int t = threadIdx.x, w = t >> 6, l = t & 63;

  const int a0 = (nb * 128) / 50;
  float* w2s = (float*)(smem + 34048);
  for (int i = t; i < 600; i += 256) {
    const int j = i / 150, a = a0 + j;
    w2s[i] = (a < 20) ? W2[a * 150 + (i - j * 150)] : 0.f;
  }

  // staging: chunk = 8 rows (1KB); lane -> row chunk*8+(l>>3), phys slot l&7
  // holding logical k-slot (l&7)^(l>>3).
  const int lr = l >> 3;
  const int ksl = (l & 7) ^ lr;
  const _Float16* gA = xn + (size_t)(mb * 128 + lr) * 1024 + ksl * 8;
  const _Float16* gB = wB + (size_t)(nb * 128 + lr) * 1024 + ksl * 8;

  const int rowA = ((w >> 1) * 64) + (l & 15);
  const int rowB = ((w & 1) * 64) + (l & 15);
  const int kq = l >> 4;
  const int xa = rowA & 7, xb = rowB & 7;
  const char* pA = smem + rowA * 128;
  const char* pB = smem + 16384 + rowB * 128;

  f4 acc[4][4];
  {
    f4 z = {0.f, 0.f, 0.f, 0.f};
#pragma unroll
    for (int mt = 0; mt < 4; ++mt)
#pragma unroll
      for (int nt = 0; nt < 4; ++nt) acc[mt][nt] = z;
  }

  for (int kt = 0; kt < 16; ++kt) {
#pragma unroll
    for (int i = 0; i < 4; ++i) {
      const int chunk = w * 4 + i;
      cp16(gA + (size_t)chunk * 8192 + kt * 64, smem + chunk * 1024);
      cp16(gB + (size_t)chunk * 8192 + kt * 64, smem + 16384 + chunk * 1024);
    }
    __syncthreads();
#pragma unroll
    for (int ks = 0; ks < 2; ++ks) {
      h8 af[4], bf[4];
      const int sl = ks * 4 + kq;
#pragma unroll
      for (int mt = 0; mt < 4; ++mt)
        af[mt] = *(const h8*)(pA + mt * 2048 + ((sl ^ xa) << 4));
#pragma unroll
      for (int nt = 0; nt < 4; ++nt)
        bf[nt] = *(const h8*)(pB + nt * 2048 + ((sl ^ xb) << 4));
#pragma unroll
      for (int mt = 0; mt < 4; ++mt)
#pragma unroll
        for (int nt = 0; nt < 4; ++nt)
          acc[mt][nt] = __builtin_amdgcn_mfma_f32_16x16x32_f16(
              af[mt], bf[nt], acc[mt][nt], 0, 0, 0);
    }
    __syncthreads();
  }

  // off_total: packed n = a*50+h -> b1[n] directly; pad rows are zero.
  float offt[4];
#pragma unroll
  for (int nt = 0; nt < 4; ++nt) {
    const int n = nb * 128 + rowB + nt * 16;
    offt[nt] = offacc[n] + ((n < 1000) ? b1[n] : 0.f);
  }

  // per-thread dot assignment: 64 tokens x 4 adapter slots
  const int ml = t >> 2, j = t & 3;
  const int a = a0 + j;
  const int c0 = nb * 128;
  int cs = a * 50, ce = cs + 50;
  if (cs < c0) cs = c0;
  if (ce > c0 + 128) ce = c0 + 128;
  const bool act = (a < 20) && (cs < ce);
  const int lo = cs - c0;
  const int len = act ? (ce - cs) : 0;
  const int h0 = cs - a * 50;
  const float* wrow = w2s + j * 150 + h0 * 3;

  float* hm = (float*)smem;  // [64][133]
  const int mrl = (l >> 4) * 4;
  const int ncol = (w & 1) * 64 + (l & 15);
#pragma unroll
  for (int p = 0; p < 2; ++p) {
    if (p) __syncthreads();
    if ((w >> 1) == p) {
#pragma unroll
      for (int mt = 0; mt < 4; ++mt)
#pragma unroll
        for (int nt = 0; nt < 4; ++nt)
#pragma unroll
          for (int r = 0; r < 4; ++r)
            hm[(mrl + mt * 16 + r) * 133 + (ncol + nt * 16)] =
                fmaxf(acc[mt][nt][r] + offt[nt], 0.f);
    }
    __syncthreads();
    if (act) {
      const float* hr = hm + ml * 133 + lo;
      float o0 = 0.f, o1 = 0.f, o2 = 0.f;
      for (int i = 0; i < len; ++i) {
        const float hv = hr[i];
        o0 += hv * wrow[i * 3 + 0];
        o1 += hv * wrow[i * 3 + 1];
        o2 += hv * wrow[i * 3 + 2];
      }
      const int tok = mb * 128 + p * 64 + ml;
      const int b = tok >> 11, s = tok & 2047;
      float* op = out + ((size_t)(b * 20 + a) * 2048 + (size_t)s) * 3;
      atomicAdd(op + 0, o0);
      atomicAdd(op + 1, o1);
      atomicAdd(op + 2, o2);
    }
  }
}

// ---------------- kernel 4: +b2, capsule squash over A, in place ------------
__global__ __launch_bounds__(256) void squash_kernel(
    float* __restrict__ out, const float* __restrict__ b2) {
  const int idx = blockIdx.x * 256 + threadIdx.x;  // 0 .. 16*6144-1
  const int b = idx / 6144;
  const int rem = idx - b * 6144;
  const int oi = rem % 3;
  float v[20];
  float sq = 0.f;
#pragma unroll
  for (int a = 0; a < 20; ++a) {
    v[a] = out[((size_t)(b * 20 + a)) * 6144 + rem] + b2[a * 3 + oi];
    sq += v[a] * v[a];
  }
  const float f = sqrtf(sq) / (1.f + sq);  // (sq/(1+sq))*rsqrt(sq), safe at 0
#pragma unroll
  for (int a = 0; a < 20; ++a)
    out[((size_t)(b * 20 + a)) * 6144 + rem] = v[a] * f;
}

// ---------------------------------------------------------------------------
extern "C" void kernel_launch(void* const* d_in, const int* in_sizes, int n_in,
                              void* d_out, int out_size, void* d_ws,
                              size_t ws_size, hipStream_t stream) {
  const float* x    = (const float*)d_in[0];  // [16,2048,1024]
  const float* ln_g = (const float*)d_in[1];  // [20,1024]
  const float* ln_b = (const float*)d_in[2];  // [20,1024]
  const float* W1   = (const float*)d_in[3];  // [20,1024,50]
  const float* b1   = (const float*)d_in[4];  // [20,50]
  const float* W2   = (const float*)d_in[5];  // [20,50,3]
  const float* b2   = (const float*)d_in[6];  // [20,3]
  float* out = (float*)d_out;                 // [16,20,6144]

  char* ws = (char*)d_ws;
  float* offacc = (float*)ws;                       // 1024 f32 @ 0
  _Float16* wBw = (_Float16*)(ws + 4096);           // 1024*1024 fp16 (2 MB)
  _Float16* xnw = (_Float16*)(ws + 4096 + 2097152); // 32768*1024 fp16 (67 MB)

  hipMemsetAsync(offacc, 0, 1024 * sizeof(float), stream);
  hipMemsetAsync(out, 0, (size_t)out_size * sizeof(float), stream);
  prep_w<<<dim3(20, 16), 256, 0, stream>>>(ln_g, ln_b, W1, wBw, offacc);
  ln_kernel<<<8192, 256, 0, stream>>>(x, xnw);
  gemm_kernel<<<2048, 256, 0, stream>>>(xnw, wBw, offacc, b1, W2, out);
  squash_kernel<<<384, 256, 0, stream>>>(out, b2);
}

// Round 7
// 303.939 us; speedup vs baseline: 1.3962x; 1.0234x over previous
//
#include <hip/hip_runtime.h>
#include <hip/hip_bf16.h>
#include <stdint.h>

// ---------------------------------------------------------------------------
// CapsuleLayerSemantic: LN -> per-adapter (W1,relu,W2) -> capsule squash over A
// B=16 S=2048 NX=1024 A=20 H=50 O=3.  M = 32768 tokens.
// R7: 4 dispatches (was 6) — no memsets: prep writes exact off-partials
//     (offpart[16][1024], summed in gemm); epilogue direct-stores full
//     adapters, atomics only for the 7 boundary-split adapters whose out-
//     slices are zeroed by extra prep blocks. ln reads made unit-stride.
//     gemm core unchanged (XCD swizzle, packed N=1024, 128x128, f16 MFMA).
// ---------------------------------------------------------------------------

typedef _Float16 h8 __attribute__((ext_vector_type(8)));
typedef float f4 __attribute__((ext_vector_type(4)));
typedef __attribute__((address_space(1))) void gvoid;
typedef __attribute__((address_space(3))) void lvoid;

__device__ __forceinline__ void cp16(const void* g, void* l) {
  __builtin_amdgcn_global_load_lds((gvoid*)g, (lvoid*)l, 16, 0, 0);
}

// ---------------- kernel 1: layernorm + fp16 cast (one wave per token) ------
// Unit-stride: lane l loads float4 xr[l+64i] (elements 4l.. / +256..),
// stores the same elements as uint2 at matching offsets (8B unit stride).
__global__ __launch_bounds__(256) void ln_kernel(const float* __restrict__ x,
                                                 _Float16* __restrict__ xn) {
  const int t = threadIdx.x, w = t >> 6, l = t & 63;
  const int tok = blockIdx.x * 4 + w;
  const float4* xr = (const float4*)(x + (size_t)tok * 1024);
  float4 v0 = xr[l], v1 = xr[64 + l], v2 = xr[128 + l], v3 = xr[192 + l];
  float s1 = (v0.x + v0.y + v0.z + v0.w) + (v1.x + v1.y + v1.z + v1.w) +
             (v2.x + v2.y + v2.z + v2.w) + (v3.x + v3.y + v3.z + v3.w);
  float s2 = v0.x * v0.x + v0.y * v0.y + v0.z * v0.z + v0.w * v0.w;
  s2 += v1.x * v1.x + v1.y * v1.y + v1.z * v1.z + v1.w * v1.w;
  s2 += v2.x * v2.x + v2.y * v2.y + v2.z * v2.z + v2.w * v2.w;
  s2 += v3.x * v3.x + v3.y * v3.y + v3.z * v3.z + v3.w * v3.w;
#pragma unroll
  for (int m = 32; m > 0; m >>= 1) {
    s1 += __shfl_xor(s1, m);
    s2 += __shfl_xor(s2, m);
  }
  const float mu = s1 * 0.0009765625f;
  const float var = s2 * 0.0009765625f - mu * mu;
  const float inv = rsqrtf(var + 1e-5f);
  uint2* xw = (uint2*)(xn + (size_t)tok * 1024);
  union { _Float16 h[4]; uint2 u; } q;
#define CVT_STORE(V, OFF)                                   \
  q.h[0] = (_Float16)((V.x - mu) * inv);                    \
  q.h[1] = (_Float16)((V.y - mu) * inv);                    \
  q.h[2] = (_Float16)((V.z - mu) * inv);                    \
  q.h[3] = (_Float16)((V.w - mu) * inv);                    \
  xw[(OFF) + l] = q.u;
  CVT_STORE(v0, 0)
  CVT_STORE(v1, 64)
  CVT_STORE(v2, 128)
  CVT_STORE(v3, 192)
#undef CVT_STORE
}

// ---------------- kernel 2: prep + out-slice zeroing ------------------------
// blocks [0,320): (a = b/16, ky = b%16): W1*ln_g transpose -> packed wB fp16,
//   exact off partial for this k-chunk -> offpart[ky][a*50+h] (no atomics).
//   a==0 blocks also zero wB pad rows 1000..1023 for their k-chunk.
// blocks [320,432): zero the out-slices of the 7 boundary-split adapters
//   {2,5,7,10,12,15,17} (only those receive atomicAdd in the gemm epilogue).
__global__ __launch_bounds__(256) void prep_w(const float* __restrict__ ln_g,
                                              const float* __restrict__ ln_b,
                                              const float* __restrict__ W1,
                                              _Float16* __restrict__ wB,
                                              float* __restrict__ offpart,
                                              float* __restrict__ out) {
  const int t = threadIdx.x;
  if (blockIdx.x >= 320) {
    static const int sa[7] = {2, 5, 7, 10, 12, 15, 17};
    const int idx = blockIdx.x - 320;        // 0..111
    const int ai = idx >> 4, bi = idx & 15;  // adapter-slot, batch
    float4* dst = (float4*)(out + ((size_t)(bi * 20 + sa[ai])) * 6144);
    const float4 z4 = {0.f, 0.f, 0.f, 0.f};
    for (int i = t; i < 1536; i += 256) dst[i] = z4;
    return;
  }
  const int a = blockIdx.x >> 4, k0 = (blockIdx.x & 15) * 64;
  __shared__ float tw[3200];  // W1[a][k0..k0+64][0..50]
  __shared__ float gg[64], bb[64], red[256];
  const float* src = W1 + (size_t)(a * 1024 + k0) * 50;
  for (int i = t; i < 3200; i += 256) tw[i] = src[i];
  if (t < 64) gg[t] = ln_g[a * 1024 + k0 + t];
  else if (t < 128) bb[t - 64] = ln_b[a * 1024 + k0 + (t - 64)];
  __syncthreads();
  const int h = t & 63, q = t >> 6;
  float po = 0.f;
  if (h < 50) {
#pragma unroll
    for (int half = 0; half < 2; ++half) {
      union { _Float16 hh[8]; uint4 u; } pk;
#pragma unroll
      for (int j = 0; j < 8; ++j) {
        const int k = q * 16 + half * 8 + j;
        const float wv = tw[k * 50 + h];
        pk.hh[j] = (_Float16)(gg[k] * wv);
        po += bb[k] * wv;
      }
      *(uint4*)(wB + (size_t)(a * 50 + h) * 1024 + k0 + q * 16 + half * 8) =
          pk.u;
    }
  }
  red[t] = po;
  __syncthreads();
  if (t < 50)
    offpart[(blockIdx.x & 15) * 1024 + a * 50 + t] =
        red[t] + red[64 + t] + red[128 + t] + red[192 + t];
  if (a == 0 && t < 192) {  // zero wB pad rows 1000..1023 for this k-chunk
    const uint4 z = {0, 0, 0, 0};
    *(uint4*)(wB + (size_t)(1000 + (t >> 3)) * 1024 + k0 + (t & 7) * 8) = z;
  }
}

// ---------------- kernel 3: GEMM + partial-adapter epilogue -----------------
// 1D grid 2048, swizzled: xcd=g&7, i=g>>3, nb=i&7, mb=xcd*32+(i>>3) — each
// XCD walks all 8 nb for one mb, so the A-tile is fetched into L2 once per mb
// and wB (2MB) stays L2-resident (R6: FETCH 287->47MB). 128x128 tile, BK=64,
// mfma_f32_16x16x32_f16, 4 waves 2x2, XOR-swizzled LDS, A/B via
// global_load_lds width-16. Epilogue: full adapters direct-store; boundary-
// split adapters atomicAdd onto pre-zeroed slices.
__global__ __launch_bounds__(256, 4) void gemm_kernel(
    const _Float16* __restrict__ xn, const _Float16* __restrict__ wB,
    const float* __restrict__ offpart, const float* __restrict__ b1,
    const float* __restrict__ W2, float* __restrict__ out) {
  __shared__ __align__(16) char smem[36448];
  // [0,16384) sA | [16384,32768) sB | reuse: hm=float[64][133]=34048
  // [34048,36448) w2s: 600 f32 (W2 for adapters a0..a0+3)
  const int g = blockIdx.x;
  const int xcd = g & 7, i0 = g >> 3;
  const int nb = i0 & 7;
  const int mb = xcd * 32 + (i0 >> 3);
  const int t = threadIdx.x, w = t >> 6, l = t & 63;

  const int a0 = (nb * 128) / 50;
  float* w2s = (float*)(smem + 34048);
  for (int i = t; i < 600; i += 256) {
    const int j = i / 150, a = a0 + j;
    w2s[i] = (a < 20) ? W2[a * 150 + (i - j * 150)] : 0.f;
  }

  // staging: chunk = 8 rows (1KB); lane -> row chunk*8+(l>>3), phys slot l&7
  // holding logical k-slot (l&7)^(l>>3).
  const int lr = l >> 3;
  const int ksl = (l & 7) ^ lr;
  const _Float16* gA = xn + (size_t)(mb * 128 + lr) * 1024 + ksl * 8;
  const _Float16* gB = wB + (size_t)(nb * 128 + lr) * 1024 + ksl * 8;

  const int rowA = ((w >> 1) * 64) + (l & 15);
  const int rowB = ((w & 1) * 64) + (l & 15);
  const int kq = l >> 4;
  const int xa = rowA & 7, xb = rowB & 7;
  const char* pA = smem + rowA * 128;
  const char* pB = smem + 16384 + rowB * 128;

  f4 acc[4][4];
  {
    f4 z = {0.f, 0.f, 0.f, 0.f};
#pragma unroll
    for (int mt = 0; mt < 4; ++mt)
#pragma unroll
      for (int nt = 0; nt < 4; ++nt) acc[mt][nt] = z;
  }

  for (int kt = 0; kt < 16; ++kt) {
#pragma unroll
    for (int i = 0; i < 4; ++i) {
      const int chunk = w * 4 + i;
      cp16(gA + (size_t)chunk * 8192 + kt * 64, smem + chunk * 1024);
      cp16(gB + (size_t)chunk * 8192 + kt * 64, smem + 16384 + chunk * 1024);
    }
    __syncthreads();
#pragma unroll
    for (int ks = 0; ks < 2; ++ks) {
      h8 af[4], bf[4];
      const int sl = ks * 4 + kq;
#pragma unroll
      for (int mt = 0; mt < 4; ++mt)
        af[mt] = *(const h8*)(pA + mt * 2048 + ((sl ^ xa) << 4));
#pragma unroll
      for (int nt = 0; nt < 4; ++nt)
        bf[nt] = *(const h8*)(pB + nt * 2048 + ((sl ^ xb) << 4));
#pragma unroll
      for (int mt = 0; mt < 4; ++mt)
#pragma unroll
        for (int nt = 0; nt < 4; ++nt)
          acc[mt][nt] = __builtin_amdgcn_mfma_f32_16x16x32_f16(
              af[mt], bf[nt], acc[mt][nt], 0, 0, 0);
    }
    __syncthreads();
  }

  // off_total[nt] = b1[n] + sum_{c<16} offpart[c][n]  (4KB tables, L2-hot)
  float offt[4];
  int ncols[4];
#pragma unroll
  for (int nt = 0; nt < 4; ++nt) {
    ncols[nt] = nb * 128 + rowB + nt * 16;
    offt[nt] = (ncols[nt] < 1000) ? b1[ncols[nt]] : 0.f;
  }
#pragma unroll
  for (int c = 0; c < 16; ++c)
#pragma unroll
    for (int nt = 0; nt < 4; ++nt) offt[nt] += offpart[c * 1024 + ncols[nt]];

  // per-thread dot assignment: 64 tokens x 4 adapter slots
  const int ml = t >> 2, j = t & 3;
  const int a = a0 + j;
  const int c0 = nb * 128;
  int cs = a * 50, ce = cs + 50;
  if (cs < c0) cs = c0;
  if (ce > c0 + 128) ce = c0 + 128;
  const bool act = (a < 20) && (cs < ce);
  const int lo = cs - c0;
  const int len = act ? (ce - cs) : 0;
  const int h0 = cs - a * 50;
  const float* wrow = w2s + j * 150 + h0 * 3;

  float* hm = (float*)smem;  // [64][133]
  const int mrl = (l >> 4) * 4;
  const int ncol = (w & 1) * 64 + (l & 15);
#pragma unroll
  for (int p = 0; p < 2; ++p) {
    if (p) __syncthreads();
    if ((w >> 1) == p) {
#pragma unroll
      for (int mt = 0; mt < 4; ++mt)
#pragma unroll
        for (int nt = 0; nt < 4; ++nt)
#pragma unroll
          for (int r = 0; r < 4; ++r)
            hm[(mrl + mt * 16 + r) * 133 + (ncol + nt * 16)] =
                fmaxf(acc[mt][nt][r] + offt[nt], 0.f);
    }
    __syncthreads();
    if (act) {
      const float* hr = hm + ml * 133 + lo;
      float o0 = 0.f, o1 = 0.f, o2 = 0.f;
      for (int i = 0; i < len; ++i) {
        const float hv = hr[i];
        o0 += hv * wrow[i * 3 + 0];
        o1 += hv * wrow[i * 3 + 1];
        o2 += hv * wrow[i * 3 + 2];
      }
      const int tok = mb * 128 + p * 64 + ml;
      const int b = tok >> 11, s = tok & 2047;
      float* op = out + ((size_t)(b * 20 + a) * 2048 + (size_t)s) * 3;
      if (len == 50) {  // adapter fully inside this nb block: direct store
        op[0] = o0; op[1] = o1; op[2] = o2;
      } else {          // boundary-split adapter: slice was pre-zeroed
        atomicAdd(op + 0, o0);
        atomicAdd(op + 1, o1);
        atomicAdd(op + 2, o2);
      }
    }
  }
}

// ---------------- kernel 4: +b2, capsule squash over A, in place ------------
__global__ __launch_bounds__(256) void squash_kernel(
    float* __restrict__ out, const float* __restrict__ b2) {
  const int idx = blockIdx.x * 256 + threadIdx.x;  // 0 .. 16*6144-1
  const int b = idx / 6144;
  const int rem = idx - b * 6144;
  const int oi = rem % 3;
  float v[20];
  float sq = 0.f;
#pragma unroll
  for (int a = 0; a < 20; ++a) {
    v[a] = out[((size_t)(b * 20 + a)) * 6144 + rem] + b2[a * 3 + oi];
    sq += v[a] * v[a];
  }
  const float f = sqrtf(sq) / (1.f + sq);  // (sq/(1+sq))*rsqrt(sq), safe at 0
#pragma unroll
  for (int a = 0; a < 20; ++a)
    out[((size_t)(b * 20 + a)) * 6144 + rem] = v[a] * f;
}

// ---------------------------------------------------------------------------
extern "C" void kernel_launch(void* const* d_in, const int* in_sizes, int n_in,
                              void* d_out, int out_size, void* d_ws,
                              size_t ws_size, hipStream_t stream) {
  const float* x    = (const float*)d_in[0];  // [16,2048,1024]
  const float* ln_g = (const float*)d_in[1];  // [20,1024]
  const float* ln_b = (const float*)d_in[2];  // [20,1024]
  const float* W1   = (const float*)d_in[3];  // [20,1024,50]
  const float* b1   = (const float*)d_in[4];  // [20,50]
  const float* W2   = (const float*)d_in[5];  // [20,50,3]
  const float* b2   = (const float*)d_in[6];  // [20,3]
  float* out = (float*)d_out;                 // [16,20,6144]

  char* ws = (char*)d_ws;
  float* offpart = (float*)ws;                        // [16][1024] f32 (64KB)
  _Float16* wBw  = (_Float16*)(ws + 65536);           // 1024*1024 fp16 (2MB)
  _Float16* xnw  = (_Float16*)(ws + 65536 + 2097152); // 32768*1024 fp16 (67MB)

  prep_w<<<432, 256, 0, stream>>>(ln_g, ln_b, W1, wBw, offpart, out);
  ln_kernel<<<8192, 256, 0, stream>>>(x, xnw);
  gemm_kernel<<<2048, 256, 0, stream>>>(xnw, wBw, offpart, b1, W2, out);
  squash_kernel<<<384, 256, 0, stream>>>(out, b2);
}